// Round 2
// baseline (606.413 us; speedup 1.0000x reference)
//
#include <hip/hip_runtime.h>
#include <stdint.h>
#include <stddef.h>

#define NN 50000
#define NE 800000
#define DD 128
#define NL 4
#define NG 512
#define NC 10

using short8 = __attribute__((ext_vector_type(8))) short;
using f32x4  = __attribute__((ext_vector_type(4))) float;

__device__ __forceinline__ float bf2f(unsigned short u) {
  union { unsigned int i; float f; } c; c.i = ((unsigned int)u) << 16; return c.f;
}
__device__ __forceinline__ unsigned short f2bf(float f) {
  union { unsigned int i; float f; } c; c.f = f;
  unsigned int i = c.i;
  return (unsigned short)((i + 0x7FFFu + ((i >> 16) & 1u)) >> 16);
}

// ---------------- x (fp32) -> bf16 copy ----------------
__global__ __launch_bounds__(256) void cvt_k(const float* __restrict__ x,
                                             unsigned short* __restrict__ xb) {
  int i = (blockIdx.x * 256 + threadIdx.x) * 4;
  if (i >= NN * DD) return;
  f32x4 v = *(const f32x4*)(x + i);
  unsigned int lo = (unsigned int)f2bf(v[0]) | ((unsigned int)f2bf(v[1]) << 16);
  unsigned int hi = (unsigned int)f2bf(v[2]) | ((unsigned int)f2bf(v[3]) << 16);
  ((unsigned int*)(xb + i))[0] = lo;
  ((unsigned int*)(xb + i))[1] = hi;
}

// ---------------- preprocessing: degree, rsqrt, CSR build ----------------

__global__ void deg_k(const int* __restrict__ col, int* __restrict__ deg) {
  int e = blockIdx.x * 256 + threadIdx.x;
  if (e < NE) atomicAdd(&deg[col[e]], 1);
}

__global__ void dinv_k(const int* __restrict__ deg, float* __restrict__ dinv) {
  int i = blockIdx.x * 256 + threadIdx.x;
  if (i < NN) dinv[i] = rsqrtf((float)(deg[i] + 1));
}

__global__ void scan1_k(const int* __restrict__ deg, int* __restrict__ csr_ptr,
                        int* __restrict__ bsum) {
  __shared__ int s[1024];
  int t = threadIdx.x; int gid = blockIdx.x * 1024 + t;
  int v = (gid < NN) ? deg[gid] : 0;
  s[t] = v; __syncthreads();
  for (int off = 1; off < 1024; off <<= 1) {
    int x = (t >= off) ? s[t - off] : 0;
    __syncthreads();
    s[t] += x;
    __syncthreads();
  }
  if (gid < NN) csr_ptr[gid] = s[t] - v;   // exclusive
  if (t == 1023) bsum[blockIdx.x] = s[1023];
}

__global__ void scan2_k(int* __restrict__ bsum) {
  int t = threadIdx.x;  // 64 threads, one wave
  int v = (t < 49) ? bsum[t] : 0;
  int incl = v;
  for (int off = 1; off < 64; off <<= 1) {
    int y = __shfl_up(incl, off, 64);
    if (t >= off) incl += y;
  }
  if (t < 49) bsum[t] = incl - v;          // exclusive block offsets
}

__global__ void scan3_k(int* __restrict__ csr_ptr, const int* __restrict__ bsum) {
  int t = threadIdx.x; int gid = blockIdx.x * 1024 + t;
  if (gid < NN) csr_ptr[gid] += bsum[blockIdx.x];
  if (gid == 0) csr_ptr[NN] = NE;
}

__global__ void fill_k(const int* __restrict__ row, const int* __restrict__ col,
                       const int* __restrict__ csr_ptr, int* __restrict__ cursor,
                       int* __restrict__ csr_src) {
  int e = blockIdx.x * 256 + threadIdx.x;
  if (e < NE) {
    int c = col[e];
    int pos = csr_ptr[c] + atomicAdd(&cursor[c], 1);
    csr_src[pos] = row[e];
  }
}

__global__ void gptr_k(const int* __restrict__ batch, int* __restrict__ gptr) {
  int i = blockIdx.x * 256 + threadIdx.x;
  if (i >= NN) return;
  int b  = batch[i];
  int bp = (i == 0) ? -1 : batch[i - 1];
  for (int g = bp + 1; g <= b; ++g) gptr[g] = i;
  if (i == NN - 1) { for (int g = b + 1; g <= NG; ++g) gptr[g] = NN; }
}

// ---------------- aggregation: agg = A_hat * h (gather via CSR) ----------------
// one wave per node; lane handles 2 feature dims (one dword = 2 bf16)
// input h is bf16 [NN,128]; output agg bf16 (consumed by MFMA GEMM); accum fp32
__global__ __launch_bounds__(256) void agg_k(const unsigned short* __restrict__ hin,
                                             unsigned short* __restrict__ agg,
                                             const int* __restrict__ csr_ptr,
                                             const int* __restrict__ csr_src,
                                             const float* __restrict__ dinv) {
  int v = blockIdx.x * 4 + (threadIdx.x >> 6);
  int lane = threadIdx.x & 63;
  if (v >= NN) return;
  float dv = dinv[v];
  unsigned int p = ((const unsigned int*)(hin + (size_t)v * DD))[lane];
  float wself = dv * dv;    // 1/deg
  float a0 = wself * bf2f((unsigned short)(p & 0xffffu));
  float a1 = wself * bf2f((unsigned short)(p >> 16));
  int e = csr_ptr[v], end = csr_ptr[v + 1];
  for (; e < end; ++e) {
    int s = csr_src[e];
    float w = dv * dinv[s];
    unsigned int q = ((const unsigned int*)(hin + (size_t)s * DD))[lane];
    a0 += w * bf2f((unsigned short)(q & 0xffffu));
    a1 += w * bf2f((unsigned short)(q >> 16));
  }
  ((unsigned int*)(agg + (size_t)v * DD))[lane] =
      (unsigned int)f2bf(a0) | ((unsigned int)f2bf(a1) << 16);
}

// ---------------- fused GEMM: out = relu(A @ W + b), A bf16, W fp32->bf16, out bf16 ----------------
// A [M,128] row-major bf16, W [128,128] row-major fp32 (k,n), out [M,128] bf16
// block = 256 (4 waves), each wave: 16 rows x 128 cols; BM = 64 rows/block
__global__ __launch_bounds__(256) void gemm_relu_k(const unsigned short* __restrict__ A,
                                                   const float* __restrict__ W,
                                                   const float* __restrict__ bias,
                                                   unsigned short* __restrict__ out,
                                                   int M) {
  __shared__ unsigned short Wt[128][136];   // transposed W (bf16), +8 pad
  int tid = threadIdx.x;
  for (int i = tid; i < 128 * 128; i += 256) {
    int k = i >> 7, n = i & 127;
    Wt[n][k] = f2bf(W[i]);
  }
  __syncthreads();

  int wave = tid >> 6, lane = tid & 63;
  int q = lane >> 4, r = lane & 15;
  int row0 = blockIdx.x * 64 + wave * 16;

  int arow = row0 + r;
  if (arow > M - 1) arow = M - 1;          // clamp: avoid OOB read, stores guarded
  const short* Arow = (const short*)A + (size_t)arow * DD;

  short8 afrag[4];
#pragma unroll
  for (int ks = 0; ks < 4; ++ks)
    afrag[ks] = *(const short8*)(Arow + ks * 32 + q * 8);

  f32x4 acc[8];
#pragma unroll
  for (int ct = 0; ct < 8; ++ct) acc[ct] = (f32x4){0.f, 0.f, 0.f, 0.f};

#pragma unroll
  for (int ks = 0; ks < 4; ++ks) {
#pragma unroll
    for (int ct = 0; ct < 8; ++ct) {
      short8 bfrag = *(const short8*)(&Wt[ct * 16 + r][ks * 32 + q * 8]);
      acc[ct] = __builtin_amdgcn_mfma_f32_16x16x32_bf16(afrag[ks], bfrag, acc[ct], 0, 0, 0);
    }
  }

  // C/D layout: col = ct*16 + (lane&15), row = row0 + (lane>>4)*4 + reg
  int orow = row0 + q * 4;
#pragma unroll
  for (int ct = 0; ct < 8; ++ct) {
    int coln = ct * 16 + r;
    float bc = bias[coln];
#pragma unroll
    for (int reg = 0; reg < 4; ++reg) {
      int rr = orow + reg;
      if (rr < M) {
        float val = acc[ct][reg] + bc;
        val = fmaxf(val, 0.f);
        out[(size_t)rr * DD + coln] = f2bf(val);
      }
    }
  }
}

// ---------------- pooling: batch is sorted -> segment sums, no atomics ----------------
__global__ __launch_bounds__(128) void pool_k(const unsigned short* __restrict__ h,
                                              const int* __restrict__ gptr,
                                              float* __restrict__ gpool) {
  int g = blockIdx.x, t = threadIdx.x;
  int beg = gptr[g], end = gptr[g + 1];
  float acc = 0.f;
  for (int v = beg; v < end; ++v) acc += bf2f(h[(size_t)v * DD + t]);
  gpool[g * DD + t] = acc;
}

// ---------------- MLP head, fp32, one block per graph ----------------
__global__ __launch_bounds__(128) void mlp_k(const float* __restrict__ gpool,
                                             const float* __restrict__ W1,
                                             const float* __restrict__ b1,
                                             const float* __restrict__ W2,
                                             const float* __restrict__ b2,
                                             const float* __restrict__ W3,
                                             const float* __restrict__ b3,
                                             float* __restrict__ out) {
  __shared__ float s_g[128], s_h1[128], s_h2[64];
  int g = blockIdx.x, t = threadIdx.x;
  s_g[t] = gpool[g * DD + t];
  __syncthreads();
  {
    float a = b1[t];
    for (int k = 0; k < 128; ++k) a += s_g[k] * W1[k * 128 + t];
    s_h1[t] = fmaxf(a, 0.f);
  }
  __syncthreads();
  if (t < 64) {
    float a = b2[t];
    for (int k = 0; k < 128; ++k) a += s_h1[k] * W2[k * 64 + t];
    s_h2[t] = fmaxf(a, 0.f);
  }
  __syncthreads();
  if (t < NC) {
    float a = b3[t];
    for (int k = 0; k < 64; ++k) a += s_h2[k] * W3[k * NC + t];
    out[g * NC + t] = a;
  }
}

// ---------------- launch ----------------

extern "C" void kernel_launch(void* const* d_in, const int* in_sizes, int n_in,
                              void* d_out, int out_size, void* d_ws, size_t ws_size,
                              hipStream_t stream) {
  const float* x     = (const float*)d_in[0];
  const int*   ei    = (const int*)d_in[1];
  const int*   batch = (const int*)d_in[2];
  const float* Wc    = (const float*)d_in[3];
  const float* bc    = (const float*)d_in[4];
  const float* W1    = (const float*)d_in[5];
  const float* b1    = (const float*)d_in[6];
  const float* W2    = (const float*)d_in[7];
  const float* b2    = (const float*)d_in[8];
  const float* W3    = (const float*)d_in[9];
  const float* b3    = (const float*)d_in[10];
  float* out = (float*)d_out;

  const int* erow = ei;        // edge_index[0] (source)
  const int* ecol = ei + NE;   // edge_index[1] (dest)

  char* w = (char*)d_ws;
  int*   deg     = (int*)w;    w += (size_t)NN * 4;
  int*   cursor  = (int*)w;    w += (size_t)NN * 4;
  int*   csr_ptr = (int*)w;    w += (size_t)(NN + 4) * 4;
  int*   bsum    = (int*)w;    w += 64 * 4;
  int*   gptr    = (int*)w;    w += (NG + 4) * 4;
  int*   csr_src = (int*)w;    w += (size_t)NE * 4;
  float* dinv    = (float*)w;  w += (size_t)NN * 4;
  float* gpool   = (float*)w;  w += (size_t)NG * DD * 4;
  w = (char*)(((uintptr_t)w + 255) & ~(uintptr_t)255);
  unsigned short* xb   = (unsigned short*)w; w += (size_t)NN * DD * 2;
  unsigned short* aggb = (unsigned short*)w; w += (size_t)NN * DD * 2;
  unsigned short* hbuf = (unsigned short*)w; w += (size_t)NN * DD * 2;

  // zero deg + cursor (adjacent at ws base)
  hipMemsetAsync(d_ws, 0, (size_t)NN * 2 * 4, stream);

  cvt_k  <<<(NN * DD / 4 + 255) / 256, 256, 0, stream>>>(x, xb);
  deg_k  <<<(NE + 255) / 256, 256, 0, stream>>>(ecol, deg);
  dinv_k <<<(NN + 255) / 256, 256, 0, stream>>>(deg, dinv);
  scan1_k<<<49, 1024, 0, stream>>>(deg, csr_ptr, bsum);
  scan2_k<<<1, 64, 0, stream>>>(bsum);
  scan3_k<<<49, 1024, 0, stream>>>(csr_ptr, bsum);
  fill_k <<<(NE + 255) / 256, 256, 0, stream>>>(erow, ecol, csr_ptr, cursor, csr_src);
  gptr_k <<<(NN + 255) / 256, 256, 0, stream>>>(batch, gptr);

  const int aggGrid  = (NN + 3) / 4;       // 4 nodes per 256-thread block
  const int gemmGrid = (NN + 63) / 64;

  for (int l = 0; l < NL; ++l) {
    const unsigned short* hin = (l == 0) ? xb : hbuf;
    agg_k<<<aggGrid, 256, 0, stream>>>(hin, aggb, csr_ptr, csr_src, dinv);
    gemm_relu_k<<<gemmGrid, 256, 0, stream>>>(aggb, Wc + (size_t)l * DD * DD,
                                              bc + (size_t)l * DD, hbuf, NN);
  }

  pool_k<<<NG, 128, 0, stream>>>(hbuf, gptr, gpool);
  mlp_k <<<NG, 128, 0, stream>>>(gpool, W1, b1, W2, b2, W3, b3, out);

  (void)in_sizes; (void)n_in; (void)out_size; (void)ws_size;
}

// Round 3
// 448.066 us; speedup vs baseline: 1.3534x; 1.3534x over previous
//
#include <hip/hip_runtime.h>
#include <stdint.h>
#include <stddef.h>

#define NN 50000
#define NE 800000
#define DD 128
#define NL 4
#define NG 512
#define NC 10

using short8 = __attribute__((ext_vector_type(8))) short;
using f32x4  = __attribute__((ext_vector_type(4))) float;

__device__ __forceinline__ float bf2f(unsigned short u) {
  union { unsigned int i; float f; } c; c.i = ((unsigned int)u) << 16; return c.f;
}
__device__ __forceinline__ unsigned short f2bf(float f) {
  union { unsigned int i; float f; } c; c.f = f;
  unsigned int i = c.i;
  return (unsigned short)((i + 0x7FFFu + ((i >> 16) & 1u)) >> 16);
}
__device__ __forceinline__ unsigned int pack2(float a, float b) {
  return (unsigned int)f2bf(a) | ((unsigned int)f2bf(b) << 16);
}

// ---------------- x (fp32) -> bf16, pre-scaled by dinv: xs = dinv * x ----------------
__global__ __launch_bounds__(256) void cvt_k(const float* __restrict__ x,
                                             const float* __restrict__ dinv,
                                             unsigned short* __restrict__ xb) {
  int i = (blockIdx.x * 256 + threadIdx.x) * 4;
  if (i >= NN * DD) return;
  float d = dinv[i >> 7];
  f32x4 v = *(const f32x4*)(x + i);
  ((unsigned int*)(xb + i))[0] = pack2(v[0] * d, v[1] * d);
  ((unsigned int*)(xb + i))[1] = pack2(v[2] * d, v[3] * d);
}

// ---------------- preprocessing: degree, rsqrt, CSR build ----------------

__global__ void deg_k(const int* __restrict__ col, int* __restrict__ deg) {
  int e = blockIdx.x * 256 + threadIdx.x;
  if (e < NE) atomicAdd(&deg[col[e]], 1);
}

__global__ void dinv_k(const int* __restrict__ deg, float* __restrict__ dinv) {
  int i = blockIdx.x * 256 + threadIdx.x;
  if (i < NN) dinv[i] = rsqrtf((float)(deg[i] + 1));
}

__global__ void scan1_k(const int* __restrict__ deg, int* __restrict__ csr_ptr,
                        int* __restrict__ bsum) {
  __shared__ int s[1024];
  int t = threadIdx.x; int gid = blockIdx.x * 1024 + t;
  int v = (gid < NN) ? deg[gid] : 0;
  s[t] = v; __syncthreads();
  for (int off = 1; off < 1024; off <<= 1) {
    int x = (t >= off) ? s[t - off] : 0;
    __syncthreads();
    s[t] += x;
    __syncthreads();
  }
  if (gid < NN) csr_ptr[gid] = s[t] - v;   // exclusive
  if (t == 1023) bsum[blockIdx.x] = s[1023];
}

__global__ void scan2_k(int* __restrict__ bsum) {
  int t = threadIdx.x;  // 64 threads, one wave
  int v = (t < 49) ? bsum[t] : 0;
  int incl = v;
  for (int off = 1; off < 64; off <<= 1) {
    int y = __shfl_up(incl, off, 64);
    if (t >= off) incl += y;
  }
  if (t < 49) bsum[t] = incl - v;          // exclusive block offsets
}

__global__ void scan3_k(int* __restrict__ csr_ptr, const int* __restrict__ bsum) {
  int t = threadIdx.x; int gid = blockIdx.x * 1024 + t;
  if (gid < NN) csr_ptr[gid] += bsum[blockIdx.x];
  if (gid == 0) csr_ptr[NN] = NE;
}

__global__ void fill_k(const int* __restrict__ row, const int* __restrict__ col,
                       const int* __restrict__ csr_ptr, int* __restrict__ cursor,
                       int* __restrict__ csr_src) {
  int e = blockIdx.x * 256 + threadIdx.x;
  if (e < NE) {
    int c = col[e];
    int pos = csr_ptr[c] + atomicAdd(&cursor[c], 1);
    csr_src[pos] = row[e];
  }
}

__global__ void gptr_k(const int* __restrict__ batch, int* __restrict__ gptr) {
  int i = blockIdx.x * 256 + threadIdx.x;
  if (i >= NN) return;
  int b  = batch[i];
  int bp = (i == 0) ? -1 : batch[i - 1];
  for (int g = bp + 1; g <= b; ++g) gptr[g] = i;
  if (i == NN - 1) { for (int g = b + 1; g <= NG; ++g) gptr[g] = NN; }
}

// ---------------- aggregation: agg[v] = dinv_v * (hs_v + sum_{s in N(v)} hs_s) ----------------
// hs is pre-scaled by dinv (hs = dinv * h). One wave per node; lane = q*16+r.
// Each 16-lane quarter-wave handles one edge per iteration with uint4 (16B) loads
// -> 4 independent gather chains in flight per wave. fp32 accum, shfl_xor reduce.
__global__ __launch_bounds__(256) void agg_k(const unsigned short* __restrict__ hs,
                                             unsigned short* __restrict__ agg,
                                             const int* __restrict__ csr_ptr,
                                             const int* __restrict__ csr_src,
                                             const float* __restrict__ dinv) {
  int v = blockIdx.x * 4 + (threadIdx.x >> 6);
  if (v >= NN) return;
  int lane = threadIdx.x & 63;
  int qg = lane >> 4, r = lane & 15;

  float a0 = 0.f, a1 = 0.f, a2 = 0.f, a3 = 0.f, a4 = 0.f, a5 = 0.f, a6 = 0.f, a7 = 0.f;
  if (qg == 0) {  // self term (hs_v), added by quarter-wave 0 only
    uint4 p = *((const uint4*)(hs + (size_t)v * DD) + r);
    a0 = bf2f((unsigned short)(p.x & 0xffffu)); a1 = bf2f((unsigned short)(p.x >> 16));
    a2 = bf2f((unsigned short)(p.y & 0xffffu)); a3 = bf2f((unsigned short)(p.y >> 16));
    a4 = bf2f((unsigned short)(p.z & 0xffffu)); a5 = bf2f((unsigned short)(p.z >> 16));
    a6 = bf2f((unsigned short)(p.w & 0xffffu)); a7 = bf2f((unsigned short)(p.w >> 16));
  }

  int e = csr_ptr[v] + qg, end = csr_ptr[v + 1];
  for (; e < end; e += 4) {
    int s = csr_src[e];
    uint4 p = *((const uint4*)(hs + (size_t)s * DD) + r);
    a0 += bf2f((unsigned short)(p.x & 0xffffu)); a1 += bf2f((unsigned short)(p.x >> 16));
    a2 += bf2f((unsigned short)(p.y & 0xffffu)); a3 += bf2f((unsigned short)(p.y >> 16));
    a4 += bf2f((unsigned short)(p.z & 0xffffu)); a5 += bf2f((unsigned short)(p.z >> 16));
    a6 += bf2f((unsigned short)(p.w & 0xffffu)); a7 += bf2f((unsigned short)(p.w >> 16));
  }

  // reduce the 4 quarter-wave partials (lanes r, r+16, r+32, r+48)
  a0 += __shfl_xor(a0, 16, 64); a0 += __shfl_xor(a0, 32, 64);
  a1 += __shfl_xor(a1, 16, 64); a1 += __shfl_xor(a1, 32, 64);
  a2 += __shfl_xor(a2, 16, 64); a2 += __shfl_xor(a2, 32, 64);
  a3 += __shfl_xor(a3, 16, 64); a3 += __shfl_xor(a3, 32, 64);
  a4 += __shfl_xor(a4, 16, 64); a4 += __shfl_xor(a4, 32, 64);
  a5 += __shfl_xor(a5, 16, 64); a5 += __shfl_xor(a5, 32, 64);
  a6 += __shfl_xor(a6, 16, 64); a6 += __shfl_xor(a6, 32, 64);
  a7 += __shfl_xor(a7, 16, 64); a7 += __shfl_xor(a7, 32, 64);

  if (qg == 0) {
    float dv = dinv[v];
    uint4 o;
    o.x = pack2(dv * a0, dv * a1);
    o.y = pack2(dv * a2, dv * a3);
    o.z = pack2(dv * a4, dv * a5);
    o.w = pack2(dv * a6, dv * a7);
    *((uint4*)(agg + (size_t)v * DD) + r) = o;
  }
}

// ---------------- fused GEMM: out = relu(A @ W + b) [optionally * dinv], bf16 out ----------------
// A [M,128] row-major bf16, W [128,128] row-major fp32 (k,n), out [M,128] bf16
// block = 256 (4 waves), each wave: 16 rows x 128 cols; BM = 64 rows/block
__global__ __launch_bounds__(256) void gemm_relu_k(const unsigned short* __restrict__ A,
                                                   const float* __restrict__ W,
                                                   const float* __restrict__ bias,
                                                   unsigned short* __restrict__ out,
                                                   const float* __restrict__ dscale,
                                                   int M) {
  __shared__ unsigned short Wt[128][136];   // transposed W (bf16), +8 pad
  int tid = threadIdx.x;
  for (int i = tid; i < 128 * 128; i += 256) {
    int k = i >> 7, n = i & 127;
    Wt[n][k] = f2bf(W[i]);
  }
  __syncthreads();

  int wave = tid >> 6, lane = tid & 63;
  int q = lane >> 4, r = lane & 15;
  int row0 = blockIdx.x * 64 + wave * 16;

  int arow = row0 + r;
  if (arow > M - 1) arow = M - 1;          // clamp: avoid OOB read, stores guarded
  const short* Arow = (const short*)A + (size_t)arow * DD;

  short8 afrag[4];
#pragma unroll
  for (int ks = 0; ks < 4; ++ks)
    afrag[ks] = *(const short8*)(Arow + ks * 32 + q * 8);

  f32x4 acc[8];
#pragma unroll
  for (int ct = 0; ct < 8; ++ct) acc[ct] = (f32x4){0.f, 0.f, 0.f, 0.f};

#pragma unroll
  for (int ks = 0; ks < 4; ++ks) {
#pragma unroll
    for (int ct = 0; ct < 8; ++ct) {
      short8 bfrag = *(const short8*)(&Wt[ct * 16 + r][ks * 32 + q * 8]);
      acc[ct] = __builtin_amdgcn_mfma_f32_16x16x32_bf16(afrag[ks], bfrag, acc[ct], 0, 0, 0);
    }
  }

  // C/D layout: col = ct*16 + (lane&15), row = row0 + (lane>>4)*4 + reg
  int orow = row0 + q * 4;
  float sc[4];
#pragma unroll
  for (int reg = 0; reg < 4; ++reg) {
    int rr = orow + reg;
    sc[reg] = (dscale && rr < M) ? dscale[rr] : 1.f;
  }
#pragma unroll
  for (int ct = 0; ct < 8; ++ct) {
    int coln = ct * 16 + r;
    float bc = bias[coln];
#pragma unroll
    for (int reg = 0; reg < 4; ++reg) {
      int rr = orow + reg;
      if (rr < M) {
        float val = fmaxf(acc[ct][reg] + bc, 0.f) * sc[reg];
        out[(size_t)rr * DD + coln] = f2bf(val);
      }
    }
  }
}

// ---------------- pooling: batch is sorted -> segment sums, no atomics ----------------
__global__ __launch_bounds__(128) void pool_k(const unsigned short* __restrict__ h,
                                              const int* __restrict__ gptr,
                                              float* __restrict__ gpool) {
  int g = blockIdx.x, t = threadIdx.x;
  int beg = gptr[g], end = gptr[g + 1];
  float acc = 0.f;
  for (int v = beg; v < end; ++v) acc += bf2f(h[(size_t)v * DD + t]);
  gpool[g * DD + t] = acc;
}

// ---------------- MLP head, fp32, one block per graph ----------------
__global__ __launch_bounds__(128) void mlp_k(const float* __restrict__ gpool,
                                             const float* __restrict__ W1,
                                             const float* __restrict__ b1,
                                             const float* __restrict__ W2,
                                             const float* __restrict__ b2,
                                             const float* __restrict__ W3,
                                             const float* __restrict__ b3,
                                             float* __restrict__ out) {
  __shared__ float s_g[128], s_h1[128], s_h2[64];
  int g = blockIdx.x, t = threadIdx.x;
  s_g[t] = gpool[g * DD + t];
  __syncthreads();
  {
    float a = b1[t];
    for (int k = 0; k < 128; ++k) a += s_g[k] * W1[k * 128 + t];
    s_h1[t] = fmaxf(a, 0.f);
  }
  __syncthreads();
  if (t < 64) {
    float a = b2[t];
    for (int k = 0; k < 128; ++k) a += s_h1[k] * W2[k * 64 + t];
    s_h2[t] = fmaxf(a, 0.f);
  }
  __syncthreads();
  if (t < NC) {
    float a = b3[t];
    for (int k = 0; k < 64; ++k) a += s_h2[k] * W3[k * NC + t];
    out[g * NC + t] = a;
  }
}

// ---------------- launch ----------------

extern "C" void kernel_launch(void* const* d_in, const int* in_sizes, int n_in,
                              void* d_out, int out_size, void* d_ws, size_t ws_size,
                              hipStream_t stream) {
  const float* x     = (const float*)d_in[0];
  const int*   ei    = (const int*)d_in[1];
  const int*   batch = (const int*)d_in[2];
  const float* Wc    = (const float*)d_in[3];
  const float* bc    = (const float*)d_in[4];
  const float* W1    = (const float*)d_in[5];
  const float* b1    = (const float*)d_in[6];
  const float* W2    = (const float*)d_in[7];
  const float* b2    = (const float*)d_in[8];
  const float* W3    = (const float*)d_in[9];
  const float* b3    = (const float*)d_in[10];
  float* out = (float*)d_out;

  const int* erow = ei;        // edge_index[0] (source)
  const int* ecol = ei + NE;   // edge_index[1] (dest)

  char* w = (char*)d_ws;
  int*   deg     = (int*)w;    w += (size_t)NN * 4;
  int*   cursor  = (int*)w;    w += (size_t)NN * 4;
  int*   csr_ptr = (int*)w;    w += (size_t)(NN + 4) * 4;
  int*   bsum    = (int*)w;    w += 64 * 4;
  int*   gptr    = (int*)w;    w += (NG + 4) * 4;
  int*   csr_src = (int*)w;    w += (size_t)NE * 4;
  float* dinv    = (float*)w;  w += (size_t)NN * 4;
  float* gpool   = (float*)w;  w += (size_t)NG * DD * 4;
  w = (char*)(((uintptr_t)w + 255) & ~(uintptr_t)255);
  unsigned short* xb   = (unsigned short*)w; w += (size_t)NN * DD * 2;
  unsigned short* aggb = (unsigned short*)w; w += (size_t)NN * DD * 2;
  unsigned short* hbuf = (unsigned short*)w; w += (size_t)NN * DD * 2;

  // zero deg + cursor (adjacent at ws base)
  hipMemsetAsync(d_ws, 0, (size_t)NN * 2 * 4, stream);

  deg_k  <<<(NE + 255) / 256, 256, 0, stream>>>(ecol, deg);
  dinv_k <<<(NN + 255) / 256, 256, 0, stream>>>(deg, dinv);
  cvt_k  <<<(NN * DD / 4 + 255) / 256, 256, 0, stream>>>(x, dinv, xb);
  scan1_k<<<49, 1024, 0, stream>>>(deg, csr_ptr, bsum);
  scan2_k<<<1, 64, 0, stream>>>(bsum);
  scan3_k<<<49, 1024, 0, stream>>>(csr_ptr, bsum);
  fill_k <<<(NE + 255) / 256, 256, 0, stream>>>(erow, ecol, csr_ptr, cursor, csr_src);
  gptr_k <<<(NN + 255) / 256, 256, 0, stream>>>(batch, gptr);

  const int aggGrid  = (NN + 3) / 4;       // 4 nodes (waves) per 256-thread block
  const int gemmGrid = (NN + 63) / 64;

  for (int l = 0; l < NL; ++l) {
    const unsigned short* hin = (l == 0) ? xb : hbuf;
    const float* dsc = (l == NL - 1) ? nullptr : dinv;   // last layer: plain h for pooling
    agg_k<<<aggGrid, 256, 0, stream>>>(hin, aggb, csr_ptr, csr_src, dinv);
    gemm_relu_k<<<gemmGrid, 256, 0, stream>>>(aggb, Wc + (size_t)l * DD * DD,
                                              bc + (size_t)l * DD, hbuf, dsc, NN);
  }

  pool_k<<<NG, 128, 0, stream>>>(hbuf, gptr, gpool);
  mlp_k <<<NG, 128, 0, stream>>>(gpool, W1, b1, W2, b2, W3, b3, out);

  (void)in_sizes; (void)n_in; (void)out_size; (void)ws_size;
}

// Round 5
// 366.648 us; speedup vs baseline: 1.6539x; 1.2221x over previous
//
#include <hip/hip_runtime.h>
#include <stdint.h>
#include <stddef.h>

#define NN 50000
#define NE 800000
#define DD 128
#define NL 4
#define NG 512
#define NC 10
#define NB 196           // buckets of 256 dest nodes: ceil(50000/256)
#define BCAP 5056        // per-bucket capacity (mean 4096, sd ~64 -> 15 sd margin)

using short8 = __attribute__((ext_vector_type(8))) short;
using f32x4  = __attribute__((ext_vector_type(4))) float;

__device__ __forceinline__ float bf2f(unsigned short u) {
  union { unsigned int i; float f; } c; c.i = ((unsigned int)u) << 16; return c.f;
}
__device__ __forceinline__ unsigned short f2bf(float f) {
  union { unsigned int i; float f; } c; c.f = f;
  unsigned int i = c.i;
  return (unsigned short)((i + 0x7FFFu + ((i >> 16) & 1u)) >> 16);
}
__device__ __forceinline__ unsigned int pack2(float a, float b) {
  return (unsigned int)f2bf(a) | ((unsigned int)f2bf(b) << 16);
}

// ---------------- pass1a: bucket histogram (LDS-aggregated) ----------------
__global__ __launch_bounds__(1024) void p1a_k(const int* __restrict__ ecol,
                                              int* __restrict__ hist) {
  __shared__ int lh[NB];
  int tid = threadIdx.x;
  if (tid < NB) lh[tid] = 0;
  __syncthreads();
  int e0 = blockIdx.x * 4096 + tid;
#pragma unroll
  for (int j = 0; j < 4; ++j) {
    int e = e0 + j * 1024;
    if (e < NE) atomicAdd(&lh[ecol[e] >> 8], 1);
  }
  __syncthreads();
  if (tid < NB && lh[tid] > 0) atomicAdd(&hist[tid], lh[tid]);
}

// ---------------- scan196: bucket bases, init cursors ----------------
__global__ __launch_bounds__(256) void scanb_k(const int* __restrict__ hist,
                                               int* __restrict__ ebase,
                                               int* __restrict__ cursor,
                                               int* __restrict__ csr_ptr) {
  __shared__ int sc[256];
  int t = threadIdx.x;
  int h = (t < NB) ? hist[t] : 0;
  sc[t] = h; __syncthreads();
  for (int off = 1; off < 256; off <<= 1) {
    int v = (t >= off) ? sc[t - off] : 0;
    __syncthreads();
    sc[t] += v;
    __syncthreads();
  }
  if (t < NB) { ebase[t] = sc[t] - h; cursor[t] = sc[t] - h; }
  if (t == NB - 1) ebase[NB] = sc[t];
  if (t == 0) csr_ptr[NN] = NE;
}

// ---------------- pass1b: place packed edges into bucket regions ----------------
__global__ __launch_bounds__(1024) void p1b_k(const int* __restrict__ erow,
                                              const int* __restrict__ ecol,
                                              int* __restrict__ cursor,
                                              unsigned int* __restrict__ ebuf) {
  __shared__ int lcnt[NB], gb[NB];
  int tid = threadIdx.x;
  if (tid < NB) lcnt[tid] = 0;
  __syncthreads();
  int e0 = blockIdx.x * 4096 + tid;
  int bk[4], sl[4]; unsigned int pk[4];
#pragma unroll
  for (int j = 0; j < 4; ++j) {
    int e = e0 + j * 1024;
    bk[j] = -1;
    if (e < NE) {
      int d = ecol[e], s = erow[e];
      bk[j] = d >> 8;
      pk[j] = ((unsigned int)(d & 255) << 16) | (unsigned int)s;
      sl[j] = atomicAdd(&lcnt[bk[j]], 1);
    }
  }
  __syncthreads();
  if (tid < NB) {
    int c = lcnt[tid];
    gb[tid] = c ? atomicAdd(&cursor[tid], c) : 0;
  }
  __syncthreads();
#pragma unroll
  for (int j = 0; j < 4; ++j)
    if (bk[j] >= 0) ebuf[gb[bk[j]] + sl[j]] = pk[j];
}

// ---------------- pass2: per-bucket counting sort + dinv + x->bf16*dinv ----------------
__global__ __launch_bounds__(1024) void p2_k(const unsigned int* __restrict__ ebuf,
                                             const int* __restrict__ ebase,
                                             const float* __restrict__ x,
                                             int* __restrict__ csr_ptr,
                                             int* __restrict__ csr_src,
                                             float* __restrict__ dinv,
                                             unsigned short* __restrict__ xb) {
  __shared__ unsigned int pr[BCAP];
  __shared__ int srcb[BCAP];
  __shared__ int hist_s[256], scn[256], lcur[256];
  __shared__ float dinv_s[256];
  int b = blockIdx.x, tid = threadIdx.x;
  int beg = ebase[b];
  int cnt = ebase[b + 1] - beg;
  if (cnt > BCAP) cnt = BCAP;   // safety clamp (never hit for this dataset)

  if (tid < 256) hist_s[tid] = 0;
  __syncthreads();
  for (int i = tid; i < cnt; i += 1024) {
    unsigned int p = ebuf[beg + i];
    pr[i] = p;
    atomicAdd(&hist_s[p >> 16], 1);
  }
  __syncthreads();
  if (tid < 256) scn[tid] = hist_s[tid];
  __syncthreads();
  for (int off = 1; off < 256; off <<= 1) {
    int v = (tid < 256 && tid >= off) ? scn[tid - off] : 0;
    __syncthreads();
    if (tid < 256) scn[tid] += v;
    __syncthreads();
  }
  if (tid < 256) {
    int ex = scn[tid] - hist_s[tid];
    lcur[tid] = ex;
    int V = b * 256 + tid;
    if (V < NN) {
      csr_ptr[V] = beg + ex;
      float dv = rsqrtf((float)(hist_s[tid] + 1));
      dinv[V] = dv;
      dinv_s[tid] = dv;
    }
  }
  __syncthreads();
  for (int i = tid; i < cnt; i += 1024) {
    unsigned int p = pr[i];
    int pos = atomicAdd(&lcur[p >> 16], 1);
    srcb[pos] = (int)(p & 0xFFFFu);
  }
  __syncthreads();
  for (int i = tid; i < cnt; i += 1024) csr_src[beg + i] = srcb[i];

  // x -> bf16 pre-scaled by dinv for this bucket's nodes
  for (int i4 = tid; i4 < 256 * 32; i4 += 1024) {
    int vl = i4 >> 5;
    int V = b * 256 + vl;
    if (V < NN) {
      float d = dinv_s[vl];
      f32x4 vx = *((const f32x4*)(x + (size_t)V * DD) + (i4 & 31));
      uint2 o;
      o.x = pack2(vx[0] * d, vx[1] * d);
      o.y = pack2(vx[2] * d, vx[3] * d);
      *((uint2*)(xb + (size_t)V * DD) + (i4 & 31)) = o;
    }
  }
}

// ---------------- gptr: graph boundaries from sorted batch ----------------
__global__ void gptr_k(const int* __restrict__ batch, int* __restrict__ gptr) {
  int i = blockIdx.x * 256 + threadIdx.x;
  if (i >= NN) return;
  int b  = batch[i];
  int bp = (i == 0) ? -1 : batch[i - 1];
  for (int g = bp + 1; g <= b; ++g) gptr[g] = i;
  if (i == NN - 1) { for (int g = b + 1; g <= NG; ++g) gptr[g] = NN; }
}

// ---------------- aggregation: agg[v] = dinv_v * (hs_v + sum_{s in N(v)} hs_s) ----------------
// hs pre-scaled by dinv. One wave/node; quarter-wave (16 lanes x 16B) per edge,
// 2-way unrolled -> 8 outstanding row gathers per wave. fp32 accum.
// NOTE: row stride is 16 uint4s (128 bf16 = 256 B). R4 bug was stride 8.
__global__ __launch_bounds__(256) void agg_k(const unsigned short* __restrict__ hs,
                                             unsigned short* __restrict__ agg,
                                             const int* __restrict__ csr_ptr,
                                             const int* __restrict__ csr_src,
                                             const float* __restrict__ dinv) {
  int v = blockIdx.x * 4 + (threadIdx.x >> 6);
  if (v >= NN) return;
  int lane = threadIdx.x & 63;
  int qg = lane >> 4, r = lane & 15;
  const uint4* rows = (const uint4*)hs;   // row v = rows[v*16 + r]

  float a0 = 0.f, a1 = 0.f, a2 = 0.f, a3 = 0.f, a4 = 0.f, a5 = 0.f, a6 = 0.f, a7 = 0.f;
  float b0 = 0.f, b1 = 0.f, b2 = 0.f, b3 = 0.f, b4 = 0.f, b5 = 0.f, b6 = 0.f, b7 = 0.f;
  if (qg == 0) {
    uint4 p = rows[(size_t)v * 16 + r];
    a0 = bf2f((unsigned short)(p.x & 0xffffu)); a1 = bf2f((unsigned short)(p.x >> 16));
    a2 = bf2f((unsigned short)(p.y & 0xffffu)); a3 = bf2f((unsigned short)(p.y >> 16));
    a4 = bf2f((unsigned short)(p.z & 0xffffu)); a5 = bf2f((unsigned short)(p.z >> 16));
    a6 = bf2f((unsigned short)(p.w & 0xffffu)); a7 = bf2f((unsigned short)(p.w >> 16));
  }

  int e = csr_ptr[v] + qg, end = csr_ptr[v + 1];
  for (; e + 4 < end; e += 8) {
    int s0 = csr_src[e];
    int s1 = csr_src[e + 4];
    uint4 p = rows[(size_t)s0 * 16 + r];
    uint4 q = rows[(size_t)s1 * 16 + r];
    a0 += bf2f((unsigned short)(p.x & 0xffffu)); a1 += bf2f((unsigned short)(p.x >> 16));
    a2 += bf2f((unsigned short)(p.y & 0xffffu)); a3 += bf2f((unsigned short)(p.y >> 16));
    a4 += bf2f((unsigned short)(p.z & 0xffffu)); a5 += bf2f((unsigned short)(p.z >> 16));
    a6 += bf2f((unsigned short)(p.w & 0xffffu)); a7 += bf2f((unsigned short)(p.w >> 16));
    b0 += bf2f((unsigned short)(q.x & 0xffffu)); b1 += bf2f((unsigned short)(q.x >> 16));
    b2 += bf2f((unsigned short)(q.y & 0xffffu)); b3 += bf2f((unsigned short)(q.y >> 16));
    b4 += bf2f((unsigned short)(q.z & 0xffffu)); b5 += bf2f((unsigned short)(q.z >> 16));
    b6 += bf2f((unsigned short)(q.w & 0xffffu)); b7 += bf2f((unsigned short)(q.w >> 16));
  }
  if (e < end) {
    int s0 = csr_src[e];
    uint4 p = rows[(size_t)s0 * 16 + r];
    a0 += bf2f((unsigned short)(p.x & 0xffffu)); a1 += bf2f((unsigned short)(p.x >> 16));
    a2 += bf2f((unsigned short)(p.y & 0xffffu)); a3 += bf2f((unsigned short)(p.y >> 16));
    a4 += bf2f((unsigned short)(p.z & 0xffffu)); a5 += bf2f((unsigned short)(p.z >> 16));
    a6 += bf2f((unsigned short)(p.w & 0xffffu)); a7 += bf2f((unsigned short)(p.w >> 16));
  }
  a0 += b0; a1 += b1; a2 += b2; a3 += b3; a4 += b4; a5 += b5; a6 += b6; a7 += b7;

  a0 += __shfl_xor(a0, 16, 64); a0 += __shfl_xor(a0, 32, 64);
  a1 += __shfl_xor(a1, 16, 64); a1 += __shfl_xor(a1, 32, 64);
  a2 += __shfl_xor(a2, 16, 64); a2 += __shfl_xor(a2, 32, 64);
  a3 += __shfl_xor(a3, 16, 64); a3 += __shfl_xor(a3, 32, 64);
  a4 += __shfl_xor(a4, 16, 64); a4 += __shfl_xor(a4, 32, 64);
  a5 += __shfl_xor(a5, 16, 64); a5 += __shfl_xor(a5, 32, 64);
  a6 += __shfl_xor(a6, 16, 64); a6 += __shfl_xor(a6, 32, 64);
  a7 += __shfl_xor(a7, 16, 64); a7 += __shfl_xor(a7, 32, 64);

  if (qg == 0) {
    float dv = dinv[v];
    uint4 o;
    o.x = pack2(dv * a0, dv * a1);
    o.y = pack2(dv * a2, dv * a3);
    o.z = pack2(dv * a4, dv * a5);
    o.w = pack2(dv * a6, dv * a7);
    *((uint4*)(agg + (size_t)v * DD) + r) = o;
  }
}

// ---------------- fused GEMM: out = relu(A @ W + b) [optionally * dinv], bf16 out ----------------
__global__ __launch_bounds__(256) void gemm_relu_k(const unsigned short* __restrict__ A,
                                                   const float* __restrict__ W,
                                                   const float* __restrict__ bias,
                                                   unsigned short* __restrict__ out,
                                                   const float* __restrict__ dscale,
                                                   int M) {
  __shared__ unsigned short Wt[128][136];   // transposed W (bf16), +8 pad
  int tid = threadIdx.x;
  for (int i = tid; i < 128 * 128; i += 256) {
    int k = i >> 7, n = i & 127;
    Wt[n][k] = f2bf(W[i]);
  }
  __syncthreads();

  int wave = tid >> 6, lane = tid & 63;
  int q = lane >> 4, r = lane & 15;
  int row0 = blockIdx.x * 64 + wave * 16;

  int arow = row0 + r;
  if (arow > M - 1) arow = M - 1;
  const short* Arow = (const short*)A + (size_t)arow * DD;

  short8 afrag[4];
#pragma unroll
  for (int ks = 0; ks < 4; ++ks)
    afrag[ks] = *(const short8*)(Arow + ks * 32 + q * 8);

  f32x4 acc[8];
#pragma unroll
  for (int ct = 0; ct < 8; ++ct) acc[ct] = (f32x4){0.f, 0.f, 0.f, 0.f};

#pragma unroll
  for (int ks = 0; ks < 4; ++ks) {
#pragma unroll
    for (int ct = 0; ct < 8; ++ct) {
      short8 bfrag = *(const short8*)(&Wt[ct * 16 + r][ks * 32 + q * 8]);
      acc[ct] = __builtin_amdgcn_mfma_f32_16x16x32_bf16(afrag[ks], bfrag, acc[ct], 0, 0, 0);
    }
  }

  int orow = row0 + q * 4;
  float sc[4];
#pragma unroll
  for (int reg = 0; reg < 4; ++reg) {
    int rr = orow + reg;
    sc[reg] = (dscale && rr < M) ? dscale[rr] : 1.f;
  }
#pragma unroll
  for (int ct = 0; ct < 8; ++ct) {
    int coln = ct * 16 + r;
    float bc = bias[coln];
#pragma unroll
    for (int reg = 0; reg < 4; ++reg) {
      int rr = orow + reg;
      if (rr < M) {
        float val = fmaxf(acc[ct][reg] + bc, 0.f) * sc[reg];
        out[(size_t)rr * DD + coln] = f2bf(val);
      }
    }
  }
}

// ---------------- pooling ----------------
__global__ __launch_bounds__(128) void pool_k(const unsigned short* __restrict__ h,
                                              const int* __restrict__ gptr,
                                              float* __restrict__ gpool) {
  int g = blockIdx.x, t = threadIdx.x;
  int beg = gptr[g], end = gptr[g + 1];
  float acc = 0.f;
  for (int v = beg; v < end; ++v) acc += bf2f(h[(size_t)v * DD + t]);
  gpool[g * DD + t] = acc;
}

// ---------------- MLP head ----------------
__global__ __launch_bounds__(128) void mlp_k(const float* __restrict__ gpool,
                                             const float* __restrict__ W1,
                                             const float* __restrict__ b1,
                                             const float* __restrict__ W2,
                                             const float* __restrict__ b2,
                                             const float* __restrict__ W3,
                                             const float* __restrict__ b3,
                                             float* __restrict__ out) {
  __shared__ float s_g[128], s_h1[128], s_h2[64];
  int g = blockIdx.x, t = threadIdx.x;
  s_g[t] = gpool[g * DD + t];
  __syncthreads();
  {
    float a = b1[t];
    for (int k = 0; k < 128; ++k) a += s_g[k] * W1[k * 128 + t];
    s_h1[t] = fmaxf(a, 0.f);
  }
  __syncthreads();
  if (t < 64) {
    float a = b2[t];
    for (int k = 0; k < 128; ++k) a += s_h1[k] * W2[k * 64 + t];
    s_h2[t] = fmaxf(a, 0.f);
  }
  __syncthreads();
  if (t < NC) {
    float a = b3[t];
    for (int k = 0; k < 64; ++k) a += s_h2[k] * W3[k * NC + t];
    out[g * NC + t] = a;
  }
}

// ---------------- launch ----------------

extern "C" void kernel_launch(void* const* d_in, const int* in_sizes, int n_in,
                              void* d_out, int out_size, void* d_ws, size_t ws_size,
                              hipStream_t stream) {
  const float* x     = (const float*)d_in[0];
  const int*   ei    = (const int*)d_in[1];
  const int*   batch = (const int*)d_in[2];
  const float* Wc    = (const float*)d_in[3];
  const float* bc    = (const float*)d_in[4];
  const float* W1    = (const float*)d_in[5];
  const float* b1    = (const float*)d_in[6];
  const float* W2    = (const float*)d_in[7];
  const float* b2    = (const float*)d_in[8];
  const float* W3    = (const float*)d_in[9];
  const float* b3    = (const float*)d_in[10];
  float* out = (float*)d_out;

  const int* erow = ei;        // edge_index[0] (source)
  const int* ecol = ei + NE;   // edge_index[1] (dest)

  char* w = (char*)d_ws;
  int*   hist    = (int*)w;    w += NB * 4;          // memset 0
  int*   cursor  = (int*)w;    w += NB * 4;          // memset 0 (overwritten by scanb)
  int*   ebase   = (int*)w;    w += (NB + 4) * 4;
  int*   csr_ptr = (int*)w;    w += (size_t)(NN + 4) * 4;
  int*   gptr    = (int*)w;    w += (NG + 4) * 4;
  int*   csr_src = (int*)w;    w += (size_t)NE * 4;
  float* dinv    = (float*)w;  w += (size_t)NN * 4;
  float* gpool   = (float*)w;  w += (size_t)NG * DD * 4;
  w = (char*)(((uintptr_t)w + 255) & ~(uintptr_t)255);
  unsigned short* xb   = (unsigned short*)w; w += (size_t)NN * DD * 2;
  unsigned short* aggb = (unsigned short*)w; w += (size_t)NN * DD * 2;
  unsigned short* hbuf = (unsigned short*)w; w += (size_t)NN * DD * 2;
  unsigned int* ebuf = (unsigned int*)aggb;  // alias: ebuf only live during preproc

  hipMemsetAsync(d_ws, 0, NB * 2 * 4, stream);   // hist + cursor

  p1a_k  <<<NB, 1024, 0, stream>>>(ecol, hist);
  scanb_k<<<1, 256, 0, stream>>>(hist, ebase, cursor, csr_ptr);
  p1b_k  <<<NB, 1024, 0, stream>>>(erow, ecol, cursor, ebuf);
  p2_k   <<<NB, 1024, 0, stream>>>(ebuf, ebase, x, csr_ptr, csr_src, dinv, xb);
  gptr_k <<<(NN + 255) / 256, 256, 0, stream>>>(batch, gptr);

  const int aggGrid  = (NN + 3) / 4;
  const int gemmGrid = (NN + 63) / 64;

  for (int l = 0; l < NL; ++l) {
    const unsigned short* hin = (l == 0) ? xb : hbuf;
    const float* dsc = (l == NL - 1) ? nullptr : dinv;
    agg_k<<<aggGrid, 256, 0, stream>>>(hin, aggb, csr_ptr, csr_src, dinv);
    gemm_relu_k<<<gemmGrid, 256, 0, stream>>>(aggb, Wc + (size_t)l * DD * DD,
                                              bc + (size_t)l * DD, hbuf, dsc, NN);
  }

  pool_k<<<NG, 128, 0, stream>>>(hbuf, gptr, gpool);
  mlp_k <<<NG, 128, 0, stream>>>(gpool, W1, b1, W2, b2, W3, b3, out);

  (void)in_sizes; (void)n_in; (void)out_size; (void)ws_size;
}